// Round 7
// baseline (178.571 us; speedup 1.0000x reference)
//
#include <hip/hip_runtime.h>
#include <hip/hip_fp16.h>

// FourierFilter: out = Re(IFFT(mask * FFT(x, axis=-1))), mask zeroes bins with
// |freq| < 10 Hz (kf <= 819 of 8192 @ 100 Hz). x: [64,128,8192] f32.
//
// Register-resident four-step FFT, two real rows packed into one complex row.
// 256 threads x 32 complex regs (packed fp32 VALU via ext_vector_type(2)).
//   phase1 (regs): spans 4096..256 on {t+256m}, deferred twiddle W^{t*brev5(m)}.
//   phase2 (regs): spans 128..8 on {256*(t>>3)+(t&7)+8m}, deferred twiddle.
//   R6: spans 4,2,1 now done IN-WAVE via __shfl_xor (lanes t^4,t^2,t^1 are in
//       the same wave) with per-lane constant twiddles W8^{o&3}, W4^{o&1}, 1;
//       MASK applied in-register at slot v=base2+8m (bin = brev13(v));
//       conjugate shuffle stages mirror for the inverse. This removes 2 of 4
//       LDS round-trips, 2 of 4 barriers, and 2 of 4 fp16 quantize events.
// LDS in fp16 (__half2, 32.5 KB, pad n+(n>>6)): 4 blocks/CU; all remaining
// patterns 2 lanes/bank (free on wave64). 2 LDS round-trips / 2 barriers total.

#define FFT_N 8192
#define NT    256
#define PHY(i) ((i) + ((i) >> 6))

typedef float v2f __attribute__((ext_vector_type(2)));

__device__ __forceinline__ v2f cmul(v2f a, v2f b){
  v2f axx = {a.x, a.x};
  v2f ayy = {a.y, a.y};
  v2f byx = {-b.y, b.x};
  return axx * b + ayy * byx;
}

__device__ __forceinline__ v2f shfl2(v2f a, int mask){
  v2f o;
  o.x = __shfl_xor(a.x, mask, 64);
  o.y = __shfl_xor(a.y, mask, 64);
  return o;
}

// d * W_32^j (or conj), j in [0,16), compile-time after unroll -> constants fold.
__device__ __forceinline__ v2f mul_w32(v2f d, int j, bool cj){
  if (j == 0) return d;
  if (j == 8) return cj ? (v2f){-d.y, d.x} : (v2f){d.y, -d.x};
  const float C[16] = {1.f, 0.98078528f, 0.92387953f, 0.83146961f, 0.70710678f,
                       0.55557023f, 0.38268343f, 0.19509032f, 0.f, -0.19509032f,
                       -0.38268343f, -0.55557023f, -0.70710678f, -0.83146961f,
                       -0.92387953f, -0.98078528f};
  const float S[16] = {0.f, -0.19509032f, -0.38268343f, -0.55557023f, -0.70710678f,
                       -0.83146961f, -0.92387953f, -0.98078528f, -1.f, -0.98078528f,
                       -0.92387953f, -0.83146961f, -0.70710678f, -0.55557023f,
                       -0.38268343f, -0.19509032f};
  v2f w = {C[j], cj ? -S[j] : S[j]};
  return cmul(d, w);
}

// DIF radix-2 stages, spans L..1 over SZ regs. Twiddle W_SZ^{j*(SZ/2/L)} == W_32^{j*16/L}.
template<int SZ, int L>
__device__ __forceinline__ void dif_rec(v2f* r){
  #pragma unroll
  for (int g = 0; g < SZ; g += 2*L){
    #pragma unroll
    for (int j = 0; j < L; ++j){
      v2f u = r[g+j], v = r[g+j+L];
      r[g+j]   = u + v;
      r[g+j+L] = mul_w32(u - v, j*(16/L), false);
    }
  }
  if constexpr (L > 1) dif_rec<SZ, L/2>(r);
}

// Inverse DIT radix-2 stages, spans 1..SZ/2 (conjugate twiddles), unnormalized.
template<int SZ, int L>
__device__ __forceinline__ void dit_rec(v2f* r){
  #pragma unroll
  for (int g = 0; g < SZ; g += 2*L){
    #pragma unroll
    for (int j = 0; j < L; ++j){
      v2f a = r[g+j];
      v2f b = mul_w32(r[g+j+L], j*(16/L), true);
      r[g+j]   = a + b;
      r[g+j+L] = a - b;
    }
  }
  if constexpr (2*L < SZ) dit_rec<SZ, 2*L>(r);
}

__host__ __device__ constexpr int brev5(int k){
  return ((k&1)<<4) | ((k&2)<<2) | (k&4) | ((k&8)>>2) | ((k&16)>>4);
}

// r[brev5(k)] *= W_8192^{cbase*k} (or conj), k=1..31.
// Two half-length chains (k=1..15 and k+16 via w16) for 2x ILP, half depth.
__device__ __forceinline__ void twiddle_scale(v2f* r, int cbase, bool cj){
  float s, c;
  __sincosf((float)cbase * -7.6699039394282061e-4f, &s, &c);  // -2*pi/8192
  if (cj) s = -s;
  const v2f w1 = {c, s};
  v2f w2q = cmul(w1, w1);
  v2f w4q = cmul(w2q, w2q);
  v2f w8q = cmul(w4q, w4q);
  v2f w16 = cmul(w8q, w8q);
  v2f wa = w1;
  r[brev5(1)]  = cmul(r[brev5(1)],  wa);
  r[brev5(17)] = cmul(r[brev5(17)], cmul(w16, wa));
  #pragma unroll
  for (int k = 2; k <= 15; ++k){
    wa = cmul(wa, w1);
    r[brev5(k)]    = cmul(r[brev5(k)],    wa);
    r[brev5(k+16)] = cmul(r[brev5(k+16)], cmul(w16, wa));
  }
  r[brev5(16)] = cmul(r[brev5(16)], w16);
}

__global__ __launch_bounds__(NT, 2)
void fourier_filter_kernel(const float* __restrict__ x, float* __restrict__ out){
  __shared__ __half2 zs[FFT_N + FFT_N/64];   // 8320 * 4B = 32.5 KB (pad every 64)
  const int t = threadIdx.x;
  const long long pair = blockIdx.x;
  const float* r0 = x + pair * (2LL * FFT_N);
  const float* r1 = r0 + FFT_N;
  v2f r[32];

  // ---- fwd phase 1: spans 4096..256 on {t + 256m} (coalesced global load) ----
  #pragma unroll
  for (int m = 0; m < 32; ++m){
    const int n = t + (m << 8);
    r[m] = (v2f){__builtin_nontemporal_load(r0 + n),
                 __builtin_nontemporal_load(r1 + n)};
  }
  dif_rec<32, 16>(r);
  twiddle_scale(r, t, false);
  #pragma unroll
  for (int m = 0; m < 32; ++m)
    zs[PHY(t + (m<<8))] = __floats2half2_rn(r[m].x, r[m].y);
  __syncthreads();

  // ---- fwd phase 2: spans 128..8 on {256*(t>>3) + (t&7) + 8m} ----
  const int base2 = ((t >> 3) << 8) | (t & 7);
  #pragma unroll
  for (int m = 0; m < 32; ++m){
    float2 f = __half22float2(zs[PHY(base2 + (m<<3))]);
    r[m] = (v2f){f.x, f.y};
  }
  dif_rec<32, 16>(r);
  twiddle_scale(r, (t & 7) << 5, false);

  // ---- in-wave spans 4,2,1 (fwd), MASK, spans 1,2,4 (inv) — no LDS ----
  const int o = t & 7;
  const int j2 = o & 3;
  const float RS = 0.70710678118654752f;
  // W_8^{j2} = (cos,sin)(-pi*j2/4): x {1,RS,0,-RS}, y {0,-RS,-1,-RS}
  const float w4x = (j2==0) ? 1.f : ((j2==1) ? RS : ((j2==2) ? 0.f : -RS));
  const float w4y = (j2==0) ? 0.f : ((j2==2) ? -1.f : -RS);

  { // fwd span 4: hi out = W8^{o&3} * (lo - hi)
    const bool hi = (o & 4) != 0;
    const v2f w = {w4x, w4y};
    #pragma unroll
    for (int m = 0; m < 32; ++m){
      v2f oth = shfl2(r[m], 4);
      v2f s  = r[m] + oth;              // lo result (lane-symmetric)
      v2f d0 = r[m] - oth;              // lo-lane: lo-hi ; hi-lane: hi-lo
      v2f d  = hi ? (v2f){-d0.x, -d0.y} : d0;
      v2f tw = cmul(d, w);
      r[m] = hi ? tw : s;
    }
  }
  { // fwd span 2: hi out = W4^{o&1} * (lo - hi);  W4^1 = -i
    const bool hi = (o & 2) != 0;
    const bool ng = (o & 1) != 0;
    #pragma unroll
    for (int m = 0; m < 32; ++m){
      v2f oth = shfl2(r[m], 2);
      v2f s  = r[m] + oth;
      v2f d0 = r[m] - oth;
      v2f d  = hi ? (v2f){-d0.x, -d0.y} : d0;
      v2f dt = ng ? (v2f){d.y, -d.x} : d;   // *(-i)
      r[m] = hi ? dt : s;
    }
  }
  { // fwd span 1 (unit twiddle)
    const bool hi = (o & 1) != 0;
    #pragma unroll
    for (int m = 0; m < 32; ++m){
      v2f oth = shfl2(r[m], 1);
      v2f s  = r[m] + oth;
      v2f d0 = r[m] - oth;
      r[m] = hi ? (v2f){-d0.x, -d0.y} : s;
    }
  }

  // ---- MASK in-register: slot v holds bin brev13(v) after full DIF ----
  #pragma unroll
  for (int m = 0; m < 32; ++m){
    const int v  = base2 + (m << 3);
    const int k  = (int)(__brev((unsigned)v) >> 19);
    const int kf = min(k, FFT_N - k);
    if (kf <= 819) r[m] = (v2f){0.f, 0.f};   // |freq| < 10 Hz
  }

  { // inv span 1 (unit twiddle): lo = a+b, hi = a-b
    const bool hi = (o & 1) != 0;
    #pragma unroll
    for (int m = 0; m < 32; ++m){
      v2f oth = shfl2(r[m], 1);
      v2f s  = r[m] + oth;                  // a+b (lane-symmetric)
      v2f d0 = r[m] - oth;                  // hi-lane: b-a -> a-b = -d0
      r[m] = hi ? (v2f){-d0.x, -d0.y} : s;
    }
  }
  { // inv span 2: bt = conj(W4^{o&1})*b = (o&1) ? i*b : b
    const bool hi = (o & 2) != 0;
    const bool ng = (o & 1) != 0;
    #pragma unroll
    for (int m = 0; m < 32; ++m){
      v2f oth = shfl2(r[m], 2);
      v2f b  = hi ? r[m] : oth;             // hi-slot value
      v2f a  = hi ? oth : r[m];             // lo-slot value
      v2f bt = ng ? (v2f){-b.y, b.x} : b;   // *(+i) when ng
      v2f ap = a + bt;
      v2f am = a - bt;
      r[m] = hi ? am : ap;
    }
  }
  { // inv span 4: bt = conj(W8^{o&3})*b
    const bool hi = (o & 4) != 0;
    const v2f wc = {w4x, -w4y};
    #pragma unroll
    for (int m = 0; m < 32; ++m){
      v2f oth = shfl2(r[m], 4);
      v2f b  = hi ? r[m] : oth;
      v2f a  = hi ? oth : r[m];
      v2f bt = cmul(b, wc);
      v2f ap = a + bt;
      v2f am = a - bt;
      r[m] = hi ? am : ap;
    }
  }

  // ---- inv phase 2: conj pre-twiddle, then DIT spans 8..128; store to LDS ----
  twiddle_scale(r, (t & 7) << 5, true);
  dit_rec<32, 1>(r);
  #pragma unroll
  for (int m = 0; m < 32; ++m)
    zs[PHY(base2 + (m<<3))] = __floats2half2_rn(r[m].x, r[m].y);
  __syncthreads();

  // ---- inv phase 1: conj pre-twiddle, DIT spans 256..4096, store global ----
  #pragma unroll
  for (int m = 0; m < 32; ++m){
    float2 f = __half22float2(zs[PHY(t + (m<<8))]);
    r[m] = (v2f){f.x, f.y};
  }
  twiddle_scale(r, t, true);
  dit_rec<32, 1>(r);
  const float invn = 1.f / (float)FFT_N;
  float* o0 = out + pair * (2LL * FFT_N);
  float* o1 = o0 + FFT_N;
  #pragma unroll
  for (int m = 0; m < 32; ++m){
    const int n = t + (m << 8);
    __builtin_nontemporal_store(r[m].x * invn, o0 + n);
    __builtin_nontemporal_store(r[m].y * invn, o1 + n);
  }
}

extern "C" void kernel_launch(void* const* d_in, const int* in_sizes, int n_in,
                              void* d_out, int out_size, void* d_ws, size_t ws_size,
                              hipStream_t stream) {
  const float* x = (const float*)d_in[0];
  float* out = (float*)d_out;
  const int total  = in_sizes[0];              // 64*128*8192
  const int npairs = total / (2 * FFT_N);      // 4096 row pairs
  hipLaunchKernelGGL(fourier_filter_kernel, dim3(npairs), dim3(NT), 0, stream,
                     x, out);
}

// Round 9
// 108.223 us; speedup vs baseline: 1.6500x; 1.6500x over previous
//
#include <hip/hip_runtime.h>
#include <hip/hip_fp16.h>

// FourierFilter: out = Re(IFFT(mask * FFT(x, axis=-1))), mask zeroes bins with
// |freq| < 10 Hz (kf <= 819 of 8192 @ 100 Hz). x: [64,128,8192] f32.
//
// Register-resident four-step FFT, two real rows packed per complex row.
// 256 threads x 32 complex regs (packed fp32 VALU via ext_vector_type(2)).
// R7: stage grouping 3+5+5 (was 5+5+3) so phase-1 chains are {4t+e+1024m},
//     e=0..3 -> global I/O is float4 (16B/lane, 16 loads + 16 stores vs 64+64
//     scalar). Phase-2 chains {1024(t>>5)+(t&31)+32m}, phase-3 {32t+e}: every
//     LDS access pattern is exactly 2 lanes/bank under pad n+(n>>6) (free on
//     wave64) — removes R5's residual 6.3e6 phase-2 conflicts.
//   phase1: 4 x FFT-8 over m + deferred twiddle W^{(4t+e)*brev3(p)}.
//   phase2: FFT-32 + deferred twiddle W_1024^{(t&31)*brev5(p)}.
//   phase3: contiguous FFT-32 fwd + MASK(brev13) + inv, fused in regs.
//   inverse mirrors (conj pre-twiddle, DIT). 4 LDS RTs / 4 barriers.
// LDS fp16 __half2 (32.5 KB) => 4 blocks/CU. Loads cached; stores nontemporal.
// R8 fix: __builtin_nontemporal_store needs clang-native vector type -> v4f
//     (ext_vector_type(4)), not HIP_vector_type float4.
// R6 lesson: shuffle-based stages regressed badly (VALUBusy 66%) — reverted.

#define FFT_N 8192
#define NT    256
#define PHY(i) ((i) + ((i) >> 6))

typedef float v2f __attribute__((ext_vector_type(2)));
typedef float v4f __attribute__((ext_vector_type(4)));

__device__ __forceinline__ v2f cmul(v2f a, v2f b){
  v2f axx = {a.x, a.x};
  v2f ayy = {a.y, a.y};
  v2f byx = {-b.y, b.x};
  return axx * b + ayy * byx;
}

// d * W_32^j (or conj), j in [0,16), compile-time after unroll -> constants fold.
__device__ __forceinline__ v2f mul_w32(v2f d, int j, bool cj){
  if (j == 0) return d;
  if (j == 8) return cj ? (v2f){-d.y, d.x} : (v2f){d.y, -d.x};
  const float C[16] = {1.f, 0.98078528f, 0.92387953f, 0.83146961f, 0.70710678f,
                       0.55557023f, 0.38268343f, 0.19509032f, 0.f, -0.19509032f,
                       -0.38268343f, -0.55557023f, -0.70710678f, -0.83146961f,
                       -0.92387953f, -0.98078528f};
  const float S[16] = {0.f, -0.19509032f, -0.38268343f, -0.55557023f, -0.70710678f,
                       -0.83146961f, -0.92387953f, -0.98078528f, -1.f, -0.98078528f,
                       -0.92387953f, -0.83146961f, -0.70710678f, -0.55557023f,
                       -0.38268343f, -0.19509032f};
  v2f w = {C[j], cj ? -S[j] : S[j]};
  return cmul(d, w);
}

// DIF radix-2 stages, spans L..1 over SZ regs. Stage twiddle W_{2L}^j == W_32^{j*16/L}.
template<int SZ, int L>
__device__ __forceinline__ void dif_rec(v2f* r){
  #pragma unroll
  for (int g = 0; g < SZ; g += 2*L){
    #pragma unroll
    for (int j = 0; j < L; ++j){
      v2f u = r[g+j], v = r[g+j+L];
      r[g+j]   = u + v;
      r[g+j+L] = mul_w32(u - v, j*(16/L), false);
    }
  }
  if constexpr (L > 1) dif_rec<SZ, L/2>(r);
}

// Inverse DIT radix-2 stages, spans 1..SZ/2 (conjugate twiddles), unnormalized.
template<int SZ, int L>
__device__ __forceinline__ void dit_rec(v2f* r){
  #pragma unroll
  for (int g = 0; g < SZ; g += 2*L){
    #pragma unroll
    for (int j = 0; j < L; ++j){
      v2f a = r[g+j];
      v2f b = mul_w32(r[g+j+L], j*(16/L), true);
      r[g+j]   = a + b;
      r[g+j+L] = a - b;
    }
  }
  if constexpr (2*L < SZ) dit_rec<SZ, 2*L>(r);
}

__host__ __device__ constexpr int brev5(int k){
  return ((k&1)<<4) | ((k&2)<<2) | (k&4) | ((k&8)>>2) | ((k&16)>>4);
}

// r[brev5(k)] *= W_8192^{cbase*k} (or conj), k=1..31 (two half-chains for ILP).
__device__ __forceinline__ void twiddle_scale(v2f* r, int cbase, bool cj){
  float s, c;
  __sincosf((float)cbase * -7.6699039394282061e-4f, &s, &c);  // -2*pi/8192
  if (cj) s = -s;
  const v2f w1 = {c, s};
  v2f w2q = cmul(w1, w1);
  v2f w4q = cmul(w2q, w2q);
  v2f w8q = cmul(w4q, w4q);
  v2f w16 = cmul(w8q, w8q);
  v2f wa = w1;
  r[brev5(1)]  = cmul(r[brev5(1)],  wa);
  r[brev5(17)] = cmul(r[brev5(17)], cmul(w16, wa));
  #pragma unroll
  for (int k = 2; k <= 15; ++k){
    wa = cmul(wa, w1);
    r[brev5(k)]    = cmul(r[brev5(k)],    wa);
    r[brev5(k+16)] = cmul(r[brev5(k+16)], cmul(w16, wa));
  }
  r[brev5(16)] = cmul(r[brev5(16)], w16);
}

// r[brev3(k)] *= w1^k, k=1..7, w1 = W_8192^c (pass conj(w1) for inverse).
// brev3: 1->4, 2->2, 3->6, 4->1, 5->5, 6->3, 7->7.
__device__ __forceinline__ void tw8(v2f* r, v2f w1){
  v2f w2 = cmul(w1, w1);
  v2f w3 = cmul(w2, w1);
  v2f w4 = cmul(w2, w2);
  v2f w5 = cmul(w4, w1);
  v2f w6 = cmul(w4, w2);
  v2f w7 = cmul(w4, w3);
  r[4] = cmul(r[4], w1);
  r[2] = cmul(r[2], w2);
  r[6] = cmul(r[6], w3);
  r[1] = cmul(r[1], w4);
  r[5] = cmul(r[5], w5);
  r[3] = cmul(r[3], w6);
  r[7] = cmul(r[7], w7);
}

__global__ __launch_bounds__(NT, 2)
void fourier_filter_kernel(const float* __restrict__ x, float* __restrict__ out){
  __shared__ __half2 zs[FFT_N + FFT_N/64];   // 8320 * 4B = 32.5 KB (pad every 64)
  const int t = threadIdx.x;
  const long long pair = blockIdx.x;
  const float* r0 = x + pair * (2LL * FFT_N);
  const float* r1 = r0 + FFT_N;
  v2f r[32];

  // W_8192^1, W_8192^2 (for chain bases 4t+1, 4t+2, 4t+3)
  const v2f W1C = {0.9999997058629f, -7.669903187e-4f};
  const v2f W2C = {0.9999988234517f, -1.5339801863e-3f};

  // ---- fwd phase 1: 4 chains c=4t+e, FFT-8 over m (n = 4t+e+1024m) ----
  #pragma unroll
  for (int m = 0; m < 8; ++m){
    const int n = 4*t + (m << 10);
    const v4f a = *reinterpret_cast<const v4f*>(r0 + n);
    const v4f b = *reinterpret_cast<const v4f*>(r1 + n);
    r[0*8+m] = (v2f){a.x, b.x};
    r[1*8+m] = (v2f){a.y, b.y};
    r[2*8+m] = (v2f){a.z, b.z};
    r[3*8+m] = (v2f){a.w, b.w};
  }
  #pragma unroll
  for (int e = 0; e < 4; ++e) dif_rec<8, 4>(r + 8*e);
  {
    float s, c;
    __sincosf((float)(4*t) * -7.6699039394282061e-4f, &s, &c);
    v2f w0 = {c, s};
    v2f wA = cmul(w0, W1C);
    v2f wB = cmul(w0, W2C);
    v2f wC = cmul(wA, W2C);
    tw8(r + 0,  w0);
    tw8(r + 8,  wA);
    tw8(r + 16, wB);
    tw8(r + 24, wC);
  }
  #pragma unroll
  for (int e = 0; e < 4; ++e)
    #pragma unroll
    for (int m = 0; m < 8; ++m)
      zs[PHY(4*t + e + (m<<10))] = __floats2half2_rn(r[8*e+m].x, r[8*e+m].y);
  __syncthreads();

  // ---- fwd phase 2: chains {1024(t>>5) + (t&31) + 32m}, FFT-32 ----
  const int base2 = ((t >> 5) << 10) | (t & 31);
  #pragma unroll
  for (int m = 0; m < 32; ++m){
    float2 f = __half22float2(zs[PHY(base2 + (m<<5))]);
    r[m] = (v2f){f.x, f.y};
  }
  dif_rec<32, 16>(r);
  twiddle_scale(r, (t & 31) << 3, false);   // W_1024^{c2*k} = W_8192^{8*c2*k}
  #pragma unroll
  for (int m = 0; m < 32; ++m)
    zs[PHY(base2 + (m<<5))] = __floats2half2_rn(r[m].x, r[m].y);
  __syncthreads();

  // ---- phase 3: contiguous FFT-32 fwd + MASK + inv, fused in regs ----
  #pragma unroll
  for (int e = 0; e < 32; ++e){
    float2 f = __half22float2(zs[PHY((t<<5) + e)]);
    r[e] = (v2f){f.x, f.y};
  }
  dif_rec<32, 16>(r);
  #pragma unroll
  for (int e = 0; e < 32; ++e){
    const int v  = (t << 5) + e;
    const int k  = (int)(__brev((unsigned)v) >> 19);   // slot v holds bin brev13(v)
    const int kf = min(k, FFT_N - k);
    if (kf <= 819) r[e] = (v2f){0.f, 0.f};             // |freq| < 10 Hz
  }
  dit_rec<32, 1>(r);
  #pragma unroll
  for (int e = 0; e < 32; ++e)
    zs[PHY((t<<5) + e)] = __floats2half2_rn(r[e].x, r[e].y);
  __syncthreads();

  // ---- inv phase 2: conj pre-twiddle, DIT ----
  #pragma unroll
  for (int m = 0; m < 32; ++m){
    float2 f = __half22float2(zs[PHY(base2 + (m<<5))]);
    r[m] = (v2f){f.x, f.y};
  }
  twiddle_scale(r, (t & 31) << 3, true);
  dit_rec<32, 1>(r);
  #pragma unroll
  for (int m = 0; m < 32; ++m)
    zs[PHY(base2 + (m<<5))] = __floats2half2_rn(r[m].x, r[m].y);
  __syncthreads();

  // ---- inv phase 1: conj pre-twiddle, 4 x DIT-8, vec4 store ----
  #pragma unroll
  for (int e = 0; e < 4; ++e)
    #pragma unroll
    for (int m = 0; m < 8; ++m){
      float2 f = __half22float2(zs[PHY(4*t + e + (m<<10))]);
      r[8*e+m] = (v2f){f.x, f.y};
    }
  {
    float s, c;
    __sincosf((float)(4*t) * -7.6699039394282061e-4f, &s, &c);
    v2f w0 = {c, -s};                        // conj(W^{4t})
    const v2f W1Cc = {W1C.x, -W1C.y};
    const v2f W2Cc = {W2C.x, -W2C.y};
    v2f wA = cmul(w0, W1Cc);
    v2f wB = cmul(w0, W2Cc);
    v2f wC = cmul(wA, W2Cc);
    tw8(r + 0,  w0);
    tw8(r + 8,  wA);
    tw8(r + 16, wB);
    tw8(r + 24, wC);
  }
  #pragma unroll
  for (int e = 0; e < 4; ++e) dit_rec<8, 1>(r + 8*e);

  const float invn = 1.f / (float)FFT_N;
  float* o0 = out + pair * (2LL * FFT_N);
  float* o1 = o0 + FFT_N;
  #pragma unroll
  for (int m = 0; m < 8; ++m){
    const int n = 4*t + (m << 10);
    v4f a, b;
    a.x = r[0*8+m].x * invn;  b.x = r[0*8+m].y * invn;
    a.y = r[1*8+m].x * invn;  b.y = r[1*8+m].y * invn;
    a.z = r[2*8+m].x * invn;  b.z = r[2*8+m].y * invn;
    a.w = r[3*8+m].x * invn;  b.w = r[3*8+m].y * invn;
    __builtin_nontemporal_store(a, reinterpret_cast<v4f*>(o0 + n));
    __builtin_nontemporal_store(b, reinterpret_cast<v4f*>(o1 + n));
  }
}

extern "C" void kernel_launch(void* const* d_in, const int* in_sizes, int n_in,
                              void* d_out, int out_size, void* d_ws, size_t ws_size,
                              hipStream_t stream) {
  const float* x = (const float*)d_in[0];
  float* out = (float*)d_out;
  const int total  = in_sizes[0];              // 64*128*8192
  const int npairs = total / (2 * FFT_N);      // 4096 row pairs
  hipLaunchKernelGGL(fourier_filter_kernel, dim3(npairs), dim3(NT), 0, stream,
                     x, out);
}